// Round 1
// baseline (1470.328 us; speedup 1.0000x reference)
//
#include <hip/hip_runtime.h>
#include <hip/hip_bf16.h>
#include <stdint.h>

typedef __attribute__((ext_vector_type(8))) __bf16 bf16x8;
typedef __attribute__((ext_vector_type(4))) float f32x4;

static constexpr int kTokens = 8192;   // B*S = 4*2048
static constexpr int kHid    = 2048;   // H
static constexpr int kInter  = 8192;   // I
static constexpr int kN1     = 16384;  // 2*I, branch-interleaved in 16-col groups

// ---------------- async global->LDS 16B copy (global_load_lds_dwordx4) ----
// LDS dest must be wave-uniform base + lane*16; we arrange staging so each
// thread's LDS ptr is exactly smem_base + flat_tid*16 within its round.
__device__ __forceinline__ void async16(const void* g, void* l) {
  using gp = const __attribute__((address_space(1))) unsigned int*;
  using lp = __attribute__((address_space(3))) unsigned int*;
  // flat->AS3 truncation is valid: LDS aperture is 4GB-aligned on gfx9+
  __builtin_amdgcn_global_load_lds((gp)(uintptr_t)g,
                                   (lp)(unsigned int)(uintptr_t)l, 16, 0, 0);
}

// ---------------- LayerNorm (f32 in) -> bf16 y --------------------------
__global__ __launch_bounds__(256) void ln_kernel(
    const float* __restrict__ x, const float* __restrict__ gamma,
    const float* __restrict__ beta, __hip_bfloat16* __restrict__ y) {
  const int t = threadIdx.x;
  const size_t row = blockIdx.x;
  const float* xr = x + row * kHid;
  float4 v0 = ((const float4*)xr)[2 * t];
  float4 v1 = ((const float4*)xr)[2 * t + 1];
  float s  = v0.x + v0.y + v0.z + v0.w + v1.x + v1.y + v1.z + v1.w;
  float s2 = v0.x*v0.x + v0.y*v0.y + v0.z*v0.z + v0.w*v0.w
           + v1.x*v1.x + v1.y*v1.y + v1.z*v1.z + v1.w*v1.w;
#pragma unroll
  for (int off = 1; off < 64; off <<= 1) {
    s  += __shfl_xor(s, off, 64);
    s2 += __shfl_xor(s2, off, 64);
  }
  __shared__ float red[8];
  const int w = t >> 6;
  if ((t & 63) == 0) { red[w] = s; red[4 + w] = s2; }
  __syncthreads();
  s  = red[0] + red[1] + red[2] + red[3];
  s2 = red[4] + red[5] + red[6] + red[7];
  const float mu = s * (1.0f / kHid);
  const float rs = rsqrtf(s2 * (1.0f / kHid) - mu * mu + 1e-6f);
  float4 g0 = ((const float4*)gamma)[2 * t], g1 = ((const float4*)gamma)[2 * t + 1];
  float4 b0 = ((const float4*)beta)[2 * t],  b1 = ((const float4*)beta)[2 * t + 1];
  union { __hip_bfloat16 h[8]; uint4 u; } pk;
  pk.h[0] = __float2bfloat16((v0.x - mu) * rs * g0.x + b0.x);
  pk.h[1] = __float2bfloat16((v0.y - mu) * rs * g0.y + b0.y);
  pk.h[2] = __float2bfloat16((v0.z - mu) * rs * g0.z + b0.z);
  pk.h[3] = __float2bfloat16((v0.w - mu) * rs * g0.w + b0.w);
  pk.h[4] = __float2bfloat16((v1.x - mu) * rs * g1.x + b1.x);
  pk.h[5] = __float2bfloat16((v1.y - mu) * rs * g1.y + b1.y);
  pk.h[6] = __float2bfloat16((v1.z - mu) * rs * g1.z + b1.z);
  pk.h[7] = __float2bfloat16((v1.w - mu) * rs * g1.w + b1.w);
  ((uint4*)(y + row * kHid))[t] = pk.u;
}

// ---------------- f32 (K x Ncols) -> bf16 transposed (N x K) -------------
// INTERLEAVE=true remaps dst row n' -> src col a*8192 + i with
// i = ((n'>>5)<<4)|(n'&15), a = (n'>>4)&1  (16-col gate/linear interleave).
template <bool INTERLEAVE>
__global__ __launch_bounds__(256) void cvt_tr(
    const float* __restrict__ src, __hip_bfloat16* __restrict__ dst,
    int K, int N) {
  __shared__ float tile[64][65];
  const int nb = blockIdx.x * 64;
  const int kb = blockIdx.y * 64;
  const int t = threadIdx.x;
#pragma unroll
  for (int it = 0; it < 16; ++it) {
    int p = t + it * 256;
    int lk = p >> 6, ln = p & 63;
    int n = nb + ln;
    int col = INTERLEAVE ? ((((n >> 4) & 1) << 13) + (((n >> 5) << 4) | (n & 15)))
                         : n;
    tile[lk][ln] = src[(size_t)(kb + lk) * N + col];
  }
  __syncthreads();
#pragma unroll
  for (int it = 0; it < 16; ++it) {
    int p = t + it * 256;
    int ln = p >> 6, lk = p & 63;
    dst[(size_t)(nb + ln) * K + kb + lk] = __float2bfloat16(tile[lk][ln]);
  }
}

// ---------------- bf16 GEMM  C = A(MxK) * B^T(NxK) -----------------------
// 128x128 tile, BK=32, 4 waves (2x2), each wave 4x4 mfma_f32_16x16x32_bf16.
// global_load_lds width=16 staging; chunk-XOR swizzle (c ^ (row>>1)&3) makes
// the ds_read_b128 frag reads 2-way-conflict only (free).
// EPI=0: plain f32 C store.  EPI=1: GeGLU -> bf16 z (ldz = N/2); even/odd
// 16-col tiles are gate/linear pairs (same lane, same reg).
template <int EPI>
__global__ __launch_bounds__(256) void gemm_bt(
    const __hip_bfloat16* __restrict__ A, const __hip_bfloat16* __restrict__ B,
    void* __restrict__ Cout, int M, int N, int K) {
  __shared__ __align__(16) char smem[128 * 32 * 2 * 2];  // As 8KB + Bs 8KB
  char* As = smem;
  char* Bs = smem + 128 * 32 * 2;

  const int t = threadIdx.x;
  const int lane = t & 63;
  const int wave = t >> 6;
  const int wm = wave >> 1, wn = wave & 1;
  const size_t m0 = (size_t)blockIdx.y * 128;
  const size_t n0 = (size_t)blockIdx.x * 128;

  // staging map: round r covers flat chunk p = t + r*256; row = p>>2,
  // chunk pos = p&3 holds global chunk (p&3)^((row>>1)&3)
  const int p0 = t, p1 = t + 256;
  const int r0 = p0 >> 2, r1 = p1 >> 2;
  const int c0 = (p0 & 3) ^ ((r0 >> 1) & 3);
  const int c1 = (p1 & 3) ^ ((r1 >> 1) & 3);
  const __hip_bfloat16* gA0 = A + (m0 + r0) * K + c0 * 8;
  const __hip_bfloat16* gA1 = A + (m0 + r1) * K + c1 * 8;
  const __hip_bfloat16* gB0 = B + (n0 + r0) * K + c0 * 8;
  const __hip_bfloat16* gB1 = B + (n0 + r1) * K + c1 * 8;
  char* lA0 = As + p0 * 16;
  char* lA1 = As + p1 * 16;
  char* lB0 = Bs + p0 * 16;
  char* lB1 = Bs + p1 * 16;

  f32x4 acc[4][4] = {};

  // frag read addresses: row = (wm|wn)*64 + i*16 + col; swizzle reduces to
  // (col>>1)&3 since the i*16 / 64 offsets are 0 mod 8
  const int col = lane & 15, q = lane >> 4;
  const int chunk = (q ^ ((col >> 1) & 3)) * 16;
  const char* rdA = As + (wm * 64 + col) * 64 + chunk;
  const char* rdB = Bs + (wn * 64 + col) * 64 + chunk;

  for (int k0 = 0; k0 < K; k0 += 32) {
    async16(gA0, lA0);
    async16(gA1, lA1);
    async16(gB0, lB0);
    async16(gB1, lB1);
    gA0 += 32; gA1 += 32; gB0 += 32; gB1 += 32;
    __syncthreads();  // drains vmcnt (async copies) before LDS reads
    bf16x8 af[4], bf[4];
#pragma unroll
    for (int i = 0; i < 4; ++i) {
      af[i] = *(const bf16x8*)(rdA + i * 1024);
      bf[i] = *(const bf16x8*)(rdB + i * 1024);
    }
#pragma unroll
    for (int i = 0; i < 4; ++i)
#pragma unroll
      for (int j = 0; j < 4; ++j)
        acc[i][j] = __builtin_amdgcn_mfma_f32_16x16x32_bf16(af[i], bf[j],
                                                            acc[i][j], 0, 0, 0);
    __syncthreads();  // protect LDS from next iteration's staging
  }

  // C/D layout: col = lane&15, row = (lane>>4)*4 + reg   [m89-verified]
  const int mrow = (int)m0 + wm * 64 + q * 4;
  if (EPI == 0) {
    float* Cf = (float*)Cout;
#pragma unroll
    for (int i = 0; i < 4; ++i)
#pragma unroll
      for (int j = 0; j < 4; ++j) {
        size_t base = (size_t)(mrow + i * 16) * N + n0 + wn * 64 + j * 16 + col;
#pragma unroll
        for (int r = 0; r < 4; ++r) Cf[base + (size_t)r * N] = acc[i][j][r];
      }
  } else {
    __hip_bfloat16* Z = (__hip_bfloat16*)Cout;
    const int ldz = N >> 1;
#pragma unroll
    for (int i = 0; i < 4; ++i)
#pragma unroll
      for (int tp = 0; tp < 2; ++tp) {
        const f32x4 gg = acc[i][2 * tp];      // gate (a=0) tile
        const f32x4 ll = acc[i][2 * tp + 1];  // linear (a=1) tile
        size_t ib = (n0 >> 1) + wn * 32 + tp * 16 + col;
        size_t base = (size_t)(mrow + i * 16) * ldz + ib;
#pragma unroll
        for (int r = 0; r < 4; ++r) {
          float xv = gg[r];
          float u = 0.7978845608028654f * (xv + 0.044715f * xv * xv * xv);
          float gel = 0.5f * xv * (1.0f + tanhf(u));
          Z[base + (size_t)r * ldz] = __float2bfloat16(gel * ll[r]);
        }
      }
  }
}

extern "C" void kernel_launch(void* const* d_in, const int* in_sizes, int n_in,
                              void* d_out, int out_size, void* d_ws, size_t ws_size,
                              hipStream_t stream) {
  const float* x     = (const float*)d_in[0];
  const float* gamma = (const float*)d_in[1];
  const float* beta  = (const float*)d_in[2];
  const float* W1    = (const float*)d_in[3];  // [H, 2, I] f32
  const float* W2    = (const float*)d_in[4];  // [I, H] f32
  float* out = (float*)d_out;

  char* ws = (char*)d_ws;
  __hip_bfloat16* yb  = (__hip_bfloat16*)ws;                    // 32 MB
  __hip_bfloat16* w1t = (__hip_bfloat16*)(ws + (32ull << 20));  // 64 MB
  __hip_bfloat16* w2t = (__hip_bfloat16*)(ws + (96ull << 20));  // 32 MB
  __hip_bfloat16* z   = (__hip_bfloat16*)(ws + (128ull << 20)); // 128 MB
  (void)in_sizes; (void)n_in; (void)out_size; (void)ws_size;

  ln_kernel<<<kTokens, 256, 0, stream>>>(x, gamma, beta, yb);
  cvt_tr<true ><<<dim3(kN1 / 64, kHid / 64), 256, 0, stream>>>(W1, w1t, kHid, kN1);
  cvt_tr<false><<<dim3(kHid / 64, kInter / 64), 256, 0, stream>>>(W2, w2t, kInter, kHid);
  gemm_bt<1><<<dim3(kN1 / 128, kTokens / 128), 256, 0, stream>>>(
      yb, w1t, (void*)z, kTokens, kN1, kHid);
  gemm_bt<0><<<dim3(kHid / 128, kTokens / 128), 256, 0, stream>>>(
      z, w2t, (void*)out, kTokens, kHid, kInter);
}

// Round 4
// 1253.641 us; speedup vs baseline: 1.1728x; 1.1728x over previous
//
#include <hip/hip_runtime.h>
#include <hip/hip_bf16.h>
#include <stdint.h>

typedef __attribute__((ext_vector_type(8))) __bf16 bf16x8;
typedef __attribute__((ext_vector_type(4))) float f32x4;

static constexpr int kTokens = 8192;   // B*S = 4*2048
static constexpr int kHid    = 2048;   // H
static constexpr int kInter  = 8192;   // I
static constexpr int kN1     = 16384;  // 2*I, branch-interleaved in 16-col groups

// ---------------- async global->LDS 16B copy (global_load_lds_dwordx4) ----
// LDS dest is wave-uniform base + lane*16. NOTE (R3 post-mortem): the
// builtin's imm offset operand does NOT behave as a plain global-address
// offset on gfx950 — keep it 0 and do pointer arithmetic.
__device__ __forceinline__ void async16(const void* g, void* l) {
  using gp = const __attribute__((address_space(1))) unsigned int*;
  using lp = __attribute__((address_space(3))) unsigned int*;
  __builtin_amdgcn_global_load_lds((gp)(uintptr_t)g,
                                   (lp)(unsigned int)(uintptr_t)l, 16, 0, 0);
}

// ---------------- LayerNorm (f32 in) -> bf16 y --------------------------
__global__ __launch_bounds__(256) void ln_kernel(
    const float* __restrict__ x, const float* __restrict__ gamma,
    const float* __restrict__ beta, __hip_bfloat16* __restrict__ y) {
  const int t = threadIdx.x;
  const size_t row = blockIdx.x;
  const float* xr = x + row * kHid;
  float4 v0 = ((const float4*)xr)[2 * t];
  float4 v1 = ((const float4*)xr)[2 * t + 1];
  float s  = v0.x + v0.y + v0.z + v0.w + v1.x + v1.y + v1.z + v1.w;
  float s2 = v0.x*v0.x + v0.y*v0.y + v0.z*v0.z + v0.w*v0.w
           + v1.x*v1.x + v1.y*v1.y + v1.z*v1.z + v1.w*v1.w;
#pragma unroll
  for (int off = 1; off < 64; off <<= 1) {
    s  += __shfl_xor(s, off, 64);
    s2 += __shfl_xor(s2, off, 64);
  }
  __shared__ float red[8];
  const int w = t >> 6;
  if ((t & 63) == 0) { red[w] = s; red[4 + w] = s2; }
  __syncthreads();
  s  = red[0] + red[1] + red[2] + red[3];
  s2 = red[4] + red[5] + red[6] + red[7];
  const float mu = s * (1.0f / kHid);
  const float rs = rsqrtf(s2 * (1.0f / kHid) - mu * mu + 1e-6f);
  float4 g0 = ((const float4*)gamma)[2 * t], g1 = ((const float4*)gamma)[2 * t + 1];
  float4 b0 = ((const float4*)beta)[2 * t],  b1 = ((const float4*)beta)[2 * t + 1];
  union { __hip_bfloat16 h[8]; uint4 u; } pk;
  pk.h[0] = __float2bfloat16((v0.x - mu) * rs * g0.x + b0.x);
  pk.h[1] = __float2bfloat16((v0.y - mu) * rs * g0.y + b0.y);
  pk.h[2] = __float2bfloat16((v0.z - mu) * rs * g0.z + b0.z);
  pk.h[3] = __float2bfloat16((v0.w - mu) * rs * g0.w + b0.w);
  pk.h[4] = __float2bfloat16((v1.x - mu) * rs * g1.x + b1.x);
  pk.h[5] = __float2bfloat16((v1.y - mu) * rs * g1.y + b1.y);
  pk.h[6] = __float2bfloat16((v1.z - mu) * rs * g1.z + b1.z);
  pk.h[7] = __float2bfloat16((v1.w - mu) * rs * g1.w + b1.w);
  ((uint4*)(y + row * kHid))[t] = pk.u;
}

// ---------------- f32 (K x Ncols) -> bf16 transposed (N x K) -------------
// INTERLEAVE=true remaps dst row n' -> src col a*8192 + i with
// i = ((n'>>5)<<4)|(n'&15), a = (n'>>4)&1  (16-col gate/linear interleave).
template <bool INTERLEAVE>
__global__ __launch_bounds__(256) void cvt_tr(
    const float* __restrict__ src, __hip_bfloat16* __restrict__ dst,
    int K, int N) {
  __shared__ float tile[64][65];
  const int nb = blockIdx.x * 64;
  const int kb = blockIdx.y * 64;
  const int t = threadIdx.x;
#pragma unroll
  for (int it = 0; it < 16; ++it) {
    int p = t + it * 256;
    int lk = p >> 6, ln = p & 63;
    int n = nb + ln;
    int col = INTERLEAVE ? ((((n >> 4) & 1) << 13) + (((n >> 5) << 4) | (n & 15)))
                         : n;
    tile[lk][ln] = src[(size_t)(kb + lk) * N + col];
  }
  __syncthreads();
#pragma unroll
  for (int it = 0; it < 16; ++it) {
    int p = t + it * 256;
    int ln = p >> 6, lk = p & 63;
    dst[(size_t)(nb + ln) * K + kb + lk] = __float2bfloat16(tile[lk][ln]);
  }
}

// ---------------- bf16 GEMM  C = A(MxK) * B^T(NxK) -----------------------
// 128x128 tile, BK=32, 4 waves (2x2), each wave 4x4 mfma_f32_16x16x32_bf16.
// global_load_lds width=16 staging (offset always 0 — see async16 note);
// chunk-XOR swizzle keeps ds_read_b128 frag reads 2-way-conflict only (free).
// EPI=0: plain f32 C store.  EPI=1: GeGLU -> bf16 z (ldz = N/2); even/odd
// 16-col tiles are gate/linear pairs (same lane, same reg).
// MINW: __launch_bounds__ min-waves/EU. GEMM2 (grid=1024=4/CU) uses 4 to
// force <=128 unified regs -> single-round residency; GEMM1 keeps 2 (no
// pressure; 8192-block grid has negligible tail).
template <int EPI, int MINW>
__global__ __launch_bounds__(256, MINW) void gemm_bt(
    const __hip_bfloat16* __restrict__ A, const __hip_bfloat16* __restrict__ B,
    void* __restrict__ Cout, int M, int N, int K) {
  __shared__ __align__(16) char smem[128 * 32 * 2 * 2];  // As 8KB + Bs 8KB
  char* As = smem;
  char* Bs = smem + 128 * 32 * 2;

  const int t = threadIdx.x;
  const int lane = t & 63;
  const int wave = t >> 6;
  const int wm = wave >> 1, wn = wave & 1;
  const size_t m0 = (size_t)blockIdx.y * 128;
  const size_t n0 = (size_t)blockIdx.x * 128;

  // staging map: round r covers flat chunk p = t + r*256; row = p>>2,
  // chunk pos = p&3 holds global chunk (p&3)^((row>>1)&3)
  const int p0 = t, p1 = t + 256;
  const int r0 = p0 >> 2, r1 = p1 >> 2;
  const int c0 = (p0 & 3) ^ ((r0 >> 1) & 3);
  const int c1 = (p1 & 3) ^ ((r1 >> 1) & 3);
  const __hip_bfloat16* gA0 = A + (m0 + r0) * K + c0 * 8;
  const __hip_bfloat16* gA1 = A + (m0 + r1) * K + c1 * 8;
  const __hip_bfloat16* gB0 = B + (n0 + r0) * K + c0 * 8;
  const __hip_bfloat16* gB1 = B + (n0 + r1) * K + c1 * 8;
  char* lA0 = As + p0 * 16;
  char* lA1 = As + p1 * 16;
  char* lB0 = Bs + p0 * 16;
  char* lB1 = Bs + p1 * 16;

  f32x4 acc[4][4] = {};

  // frag read addresses: row = (wm|wn)*64 + i*16 + col; swizzle reduces to
  // (col>>1)&3 since the i*16 / 64 offsets are 0 mod 8
  const int col = lane & 15, q = lane >> 4;
  const int chunk = (q ^ ((col >> 1) & 3)) * 16;
  const char* rdA = As + (wm * 64 + col) * 64 + chunk;
  const char* rdB = Bs + (wn * 64 + col) * 64 + chunk;

  for (int k0 = 0; k0 < K; k0 += 32) {
    async16(gA0, lA0);
    async16(gA1, lA1);
    async16(gB0, lB0);
    async16(gB1, lB1);
    gA0 += 32; gA1 += 32; gB0 += 32; gB1 += 32;
    __syncthreads();  // drains vmcnt (async copies) before LDS reads
    bf16x8 af[4], bf[4];
#pragma unroll
    for (int i = 0; i < 4; ++i) {
      af[i] = *(const bf16x8*)(rdA + i * 1024);
      bf[i] = *(const bf16x8*)(rdB + i * 1024);
    }
#pragma unroll
    for (int i = 0; i < 4; ++i)
#pragma unroll
      for (int j = 0; j < 4; ++j)
        acc[i][j] = __builtin_amdgcn_mfma_f32_16x16x32_bf16(af[i], bf[j],
                                                            acc[i][j], 0, 0, 0);
    __syncthreads();  // protect LDS from next iteration's staging
  }

  // C/D layout: col = lane&15, row = (lane>>4)*4 + reg   [m89-verified]
  const int mrow = (int)m0 + wm * 64 + q * 4;
  if (EPI == 0) {
    float* Cf = (float*)Cout;
#pragma unroll
    for (int i = 0; i < 4; ++i)
#pragma unroll
      for (int j = 0; j < 4; ++j) {
        size_t base = (size_t)(mrow + i * 16) * N + n0 + wn * 64 + j * 16 + col;
#pragma unroll
        for (int r = 0; r < 4; ++r) Cf[base + (size_t)r * N] = acc[i][j][r];
      }
  } else {
    __hip_bfloat16* Z = (__hip_bfloat16*)Cout;
    const int ldz = N >> 1;
#pragma unroll
    for (int i = 0; i < 4; ++i)
#pragma unroll
      for (int tp = 0; tp < 2; ++tp) {
        const f32x4 gg = acc[i][2 * tp];      // gate (a=0) tile
        const f32x4 ll = acc[i][2 * tp + 1];  // linear (a=1) tile
        size_t ib = (n0 >> 1) + wn * 32 + tp * 16 + col;
        size_t base = (size_t)(mrow + i * 16) * ldz + ib;
#pragma unroll
        for (int r = 0; r < 4; ++r) {
          // gelu_tanh(x) = x * sigmoid(2u), u = 0.79788456*(x + 0.044715 x^3)
          // (identical to tanh form; v_exp_f32 + rcp instead of libm tanhf)
          float xv = gg[r];
          float u = 0.7978845608028654f * xv * (1.0f + 0.044715f * xv * xv);
          float sg = __builtin_amdgcn_rcpf(1.0f + __expf(-2.0f * u));
          Z[base + (size_t)r * ldz] = __float2bfloat16(xv * sg * ll[r]);
        }
      }
  }
}

extern "C" void kernel_launch(void* const* d_in, const int* in_sizes, int n_in,
                              void* d_out, int out_size, void* d_ws, size_t ws_size,
                              hipStream_t stream) {
  const float* x     = (const float*)d_in[0];
  const float* gamma = (const float*)d_in[1];
  const float* beta  = (const float*)d_in[2];
  const float* W1    = (const float*)d_in[3];  // [H, 2, I] f32
  const float* W2    = (const float*)d_in[4];  // [I, H] f32
  float* out = (float*)d_out;

  char* ws = (char*)d_ws;
  __hip_bfloat16* yb  = (__hip_bfloat16*)ws;                    // 32 MB
  __hip_bfloat16* w1t = (__hip_bfloat16*)(ws + (32ull << 20));  // 64 MB
  __hip_bfloat16* w2t = (__hip_bfloat16*)(ws + (96ull << 20));  // 32 MB
  __hip_bfloat16* z   = (__hip_bfloat16*)(ws + (128ull << 20)); // 128 MB
  (void)in_sizes; (void)n_in; (void)out_size; (void)ws_size;

  ln_kernel<<<kTokens, 256, 0, stream>>>(x, gamma, beta, yb);
  cvt_tr<true ><<<dim3(kN1 / 64, kHid / 64), 256, 0, stream>>>(W1, w1t, kHid, kN1);
  cvt_tr<false><<<dim3(kHid / 64, kInter / 64), 256, 0, stream>>>(W2, w2t, kInter, kHid);
  gemm_bt<1, 2><<<dim3(kN1 / 128, kTokens / 128), 256, 0, stream>>>(
      yb, w1t, (void*)z, kTokens, kN1, kHid);
  gemm_bt<0, 4><<<dim3(kHid / 128, kTokens / 128), 256, 0, stream>>>(
      z, w2t, (void*)out, kTokens, kHid, kInter);
}